// Round 1
// baseline (347.144 us; speedup 1.0000x reference)
//
#include <hip/hip_runtime.h>
#include <hip/hip_bf16.h>

// ---------------------------------------------------------------------------
// CrossAttention on MI355X (gfx950)
//   text [8,512,1024] f32, features [8,1024,1024] f32
//   Q = rms(text@WqT+bq)*gq ; feats = rms(features)*gf ; K = rms(feats@WkT+bk)*gk
//   attn = softmax(Qh.KhT/8) @ Vh ; out = attn@WoT + bo   (fp32 out)
// Strategy: bf16 MFMA everywhere (16x16x32), fp32 accumulate.
// ---------------------------------------------------------------------------

typedef unsigned short u16;
typedef __bf16 bf16x8 __attribute__((ext_vector_type(8)));
typedef float f32x4 __attribute__((ext_vector_type(4)));

__device__ inline f32x4 mfma16(bf16x8 a, bf16x8 b, f32x4 c) {
    return __builtin_amdgcn_mfma_f32_16x16x32_bf16(a, b, c, 0, 0, 0);
}

// round-to-nearest-even f32 -> bf16 (bit pattern)
__device__ inline u16 f2bf(float f) {
    union { float f; unsigned u; } v; v.f = f;
    unsigned r = v.u + 0x7fffu + ((v.u >> 16) & 1u);
    return (u16)(r >> 16);
}

// async global->LDS, 16B per lane. LDS dest = wave-uniform base + lane*16.
__device__ inline void load_lds16(const void* g, void* l) {
    __builtin_amdgcn_global_load_lds(
        (const __attribute__((address_space(1))) void*)g,
        (__attribute__((address_space(3))) void*)l, 16, 0, 0);
}

// ---------------------------------------------------------------------------
// elementwise fp32 -> bf16 cast (float4 / ushort4 vectorized)
__global__ __launch_bounds__(256) void cast_bf16_kernel(const float* __restrict__ in,
                                                        u16* __restrict__ out, int n4) {
    int i = blockIdx.x * 256 + threadIdx.x;
    if (i >= n4) return;
    float4 v = ((const float4*)in)[i];
    union { u16 s[4]; uint2 v; } p;
    p.s[0] = f2bf(v.x); p.s[1] = f2bf(v.y); p.s[2] = f2bf(v.z); p.s[3] = f2bf(v.w);
    ((uint2*)out)[i] = p.v;
}

// ---------------------------------------------------------------------------
// RMSNorm over last dim (1024), fp32 in, bf16 out. One block (256 thr) per row.
__global__ __launch_bounds__(256) void rmsnorm_kernel(const float* __restrict__ in,
                                                      const float* __restrict__ g,
                                                      u16* __restrict__ out) {
    int row = blockIdx.x, tid = threadIdx.x;
    const float4* rp = (const float4*)(in + (size_t)row * 1024);
    float4 v = rp[tid];
    float ss = v.x * v.x + v.y * v.y + v.z * v.z + v.w * v.w;
    #pragma unroll
    for (int m = 1; m < 64; m <<= 1) ss += __shfl_xor(ss, m, 64);
    __shared__ float ws[4];
    if ((tid & 63) == 0) ws[tid >> 6] = ss;
    __syncthreads();
    float total = ws[0] + ws[1] + ws[2] + ws[3];
    float rs = rsqrtf(total * (1.0f / 1024.0f) + 1e-6f);
    float4 gv = ((const float4*)g)[tid];
    union { u16 s[4]; uint2 v; } p;
    p.s[0] = f2bf(v.x * rs * gv.x); p.s[1] = f2bf(v.y * rs * gv.y);
    p.s[2] = f2bf(v.z * rs * gv.z); p.s[3] = f2bf(v.w * rs * gv.w);
    ((uint2*)(out + (size_t)row * 1024))[tid] = p.v;
}

// ---------------------------------------------------------------------------
// bf16 transpose per batch: in [8][1024][1024] -> out [8][1024][1024] (d-major)
// 64x64 tiles through LDS (row stride 72 to spread banks).
__global__ __launch_bounds__(256) void transpose_kernel(const u16* __restrict__ in,
                                                        u16* __restrict__ out) {
    __shared__ __align__(16) u16 tile[64][72];
    int tid = threadIdx.x, b = blockIdx.z;
    int n0 = blockIdx.x * 64, d0 = blockIdx.y * 64;
    int r = tid >> 2, cs = (tid & 3) * 16;
    const u16* src = in + ((size_t)(b * 1024 + n0 + r)) * 1024 + d0 + cs;
    union { u16 s[8]; uint4 v; } a0, a1;
    a0.v = *(const uint4*)src;
    a1.v = *(const uint4*)(src + 8);
    #pragma unroll
    for (int i = 0; i < 8; ++i) { tile[r][cs + i] = a0.s[i]; tile[r][cs + 8 + i] = a1.s[i]; }
    __syncthreads();
    union { u16 s[8]; uint4 v; } b0, b1;
    #pragma unroll
    for (int i = 0; i < 8; ++i) { b0.s[i] = tile[cs + i][r]; b1.s[i] = tile[cs + 8 + i][r]; }
    u16* dst = out + ((size_t)(b * 1024 + d0 + r)) * 1024 + n0 + cs;
    *(uint4*)dst = b0.v;
    *(uint4*)(dst + 8) = b1.v;
}

// ---------------------------------------------------------------------------
// GEMM: C[M,N] = A[M,K] * B[N,K]^T + bias[N], bf16 in, fp32 out.
// m97 recipe: 128x128 block tile, BK=32, 4 waves each 64x64 (4x4 MFMA tiles),
// global_load_lds width=16 staging, mfma_f32_16x16x32_bf16.
__global__ __launch_bounds__(256) void gemm_bt_kernel(const u16* __restrict__ A,
                                                      const u16* __restrict__ B,
                                                      const float* __restrict__ bias,
                                                      float* __restrict__ C,
                                                      int M, int N, int K) {
    __shared__ __align__(16) u16 As[128 * 32];
    __shared__ __align__(16) u16 Bs[128 * 32];
    int tid = threadIdx.x, wave = tid >> 6, lane = tid & 63;
    int quad = lane >> 4, l15 = lane & 15;
    int wm = wave & 1, wn = wave >> 1;
    int m_blk = blockIdx.x * 128, n_blk = blockIdx.y * 128;

    f32x4 acc[4][4] = {};

    for (int k0 = 0; k0 < K; k0 += 32) {
        #pragma unroll
        for (int j = 0; j < 2; ++j) {
            int idx = j * 256 + tid;
            int row = idx >> 2, kc = (idx & 3) * 8;
            load_lds16(A + (size_t)(m_blk + row) * K + k0 + kc, As + (j * 256 + wave * 64) * 8);
            load_lds16(B + (size_t)(n_blk + row) * K + k0 + kc, Bs + (j * 256 + wave * 64) * 8);
        }
        __syncthreads();
        bf16x8 af[4], bfr[4];
        #pragma unroll
        for (int t = 0; t < 4; ++t) {
            af[t]  = *(const bf16x8*)&As[(wm * 64 + t * 16 + l15) * 32 + quad * 8];
            bfr[t] = *(const bf16x8*)&Bs[(wn * 64 + t * 16 + l15) * 32 + quad * 8];
        }
        #pragma unroll
        for (int mt = 0; mt < 4; ++mt)
            #pragma unroll
            for (int nt = 0; nt < 4; ++nt)
                acc[mt][nt] = mfma16(af[mt], bfr[nt], acc[mt][nt]);
        __syncthreads();
    }
    // epilogue: C/D layout col=lane&15, row=quad*4+reg (m89/m91 verified)
    #pragma unroll
    for (int nt = 0; nt < 4; ++nt) {
        int col = n_blk + wn * 64 + nt * 16 + l15;
        float bv = bias[col];
        #pragma unroll
        for (int mt = 0; mt < 4; ++mt) {
            int row0 = m_blk + wm * 64 + mt * 16 + quad * 4;
            #pragma unroll
            for (int r = 0; r < 4; ++r)
                C[(size_t)(row0 + r) * N + col] = acc[mt][nt][r] + bv;
        }
    }
}

// ---------------------------------------------------------------------------
// Fused flash attention. Grid (qt=8, h=16, b=8), block 256 = 4 waves.
// Each wave: 16-row Q strip (16x64), loops n-tiles of 64, online softmax.
// Q[4096,1024] bf16 (normed), K[8192,1024] bf16 (normed), Vt[b][d][n] bf16.
__global__ __launch_bounds__(256) void attn_kernel(const u16* __restrict__ Q,
                                                   const u16* __restrict__ K,
                                                   const u16* __restrict__ Vt,
                                                   u16* __restrict__ Out) {
    int b = blockIdx.z, h = blockIdx.y, qt = blockIdx.x;
    int tid = threadIdx.x, wave = tid >> 6, lane = tid & 63;
    int quad = lane >> 4, l15 = lane & 15;

    __shared__ __align__(16) u16 Plds[4][16 * 72];  // per-wave P strip, stride 72
    u16* Pw = &Plds[wave][0];

    // Q A-fragments: A[m=lane&15][k=quad*8+j] (+32 for second half of Hd=64)
    const size_t qoff = ((size_t)(b * 512 + qt * 64 + wave * 16 + l15)) * 1024 + h * 64 + quad * 8;
    bf16x8 qf0 = *(const bf16x8*)(Q + qoff);
    bf16x8 qf1 = *(const bf16x8*)(Q + qoff + 32);

    f32x4 o[4] = {};
    float m_r[4], l_r[4];
    #pragma unroll
    for (int r = 0; r < 4; ++r) { m_r[r] = -1e30f; l_r[r] = 0.0f; }

    for (int n0 = 0; n0 < 1024; n0 += 64) {
        // S = Q.K^T / 8 for 4 n-tiles of 16
        f32x4 s[4];
        #pragma unroll
        for (int nt = 0; nt < 4; ++nt) {
            const u16* kp = K + ((size_t)(b * 1024 + n0 + nt * 16 + l15)) * 1024 + h * 64 + quad * 8;
            bf16x8 kf0 = *(const bf16x8*)kp;
            bf16x8 kf1 = *(const bf16x8*)(kp + 32);
            f32x4 z = {0.0f, 0.0f, 0.0f, 0.0f};
            s[nt] = mfma16(qf0, kf0, z);
            s[nt] = mfma16(qf1, kf1, s[nt]);
        }
        #pragma unroll
        for (int nt = 0; nt < 4; ++nt)
            #pragma unroll
            for (int r = 0; r < 4; ++r) s[nt][r] *= 0.125f;

        // online softmax, rows = quad*4 + r, row spread across 16 lanes of quad
        float mnew[4], alpha[4], rowsum[4];
        #pragma unroll
        for (int r = 0; r < 4; ++r) {
            float mx = fmaxf(fmaxf(s[0][r], s[1][r]), fmaxf(s[2][r], s[3][r]));
            mx = fmaxf(mx, __shfl_xor(mx, 1, 64));
            mx = fmaxf(mx, __shfl_xor(mx, 2, 64));
            mx = fmaxf(mx, __shfl_xor(mx, 4, 64));
            mx = fmaxf(mx, __shfl_xor(mx, 8, 64));
            mnew[r] = fmaxf(m_r[r], mx);
            alpha[r] = __expf(m_r[r] - mnew[r]);
            m_r[r] = mnew[r];
            rowsum[r] = 0.0f;
        }
        #pragma unroll
        for (int nt = 0; nt < 4; ++nt)
            #pragma unroll
            for (int r = 0; r < 4; ++r) {
                float p = __expf(s[nt][r] - mnew[r]);
                rowsum[r] += p;
                Pw[(quad * 4 + r) * 72 + nt * 16 + l15] = f2bf(p);
            }
        #pragma unroll
        for (int r = 0; r < 4; ++r) {
            float rs = rowsum[r];
            rs += __shfl_xor(rs, 1, 64);
            rs += __shfl_xor(rs, 2, 64);
            rs += __shfl_xor(rs, 4, 64);
            rs += __shfl_xor(rs, 8, 64);
            l_r[r] = l_r[r] * alpha[r] + rs;
        }
        #pragma unroll
        for (int dt = 0; dt < 4; ++dt)
            #pragma unroll
            for (int r = 0; r < 4; ++r) o[dt][r] *= alpha[r];

        // P back from LDS in A-layout (wave-private; compiler orders lgkmcnt)
        bf16x8 p0 = *(const bf16x8*)&Pw[l15 * 72 + quad * 8];
        bf16x8 p1 = *(const bf16x8*)&Pw[l15 * 72 + 32 + quad * 8];
        #pragma unroll
        for (int dt = 0; dt < 4; ++dt) {
            const u16* vp = Vt + ((size_t)(b * 1024 + h * 64 + dt * 16 + l15)) * 1024 + n0 + quad * 8;
            bf16x8 v0 = *(const bf16x8*)vp;
            bf16x8 v1 = *(const bf16x8*)(vp + 32);
            o[dt] = mfma16(p0, v0, o[dt]);
            o[dt] = mfma16(p1, v1, o[dt]);
        }
    }

    // epilogue: O /= l, write bf16
    #pragma unroll
    for (int r = 0; r < 4; ++r) l_r[r] = 1.0f / l_r[r];
    #pragma unroll
    for (int dt = 0; dt < 4; ++dt)
        #pragma unroll
        for (int r = 0; r < 4; ++r) {
            size_t oi = ((size_t)(b * 512 + qt * 64 + wave * 16 + quad * 4 + r)) * 1024
                        + h * 64 + dt * 16 + l15;
            Out[oi] = f2bf(o[dt][r] * l_r[r]);
        }
}

// ---------------------------------------------------------------------------
extern "C" void kernel_launch(void* const* d_in, const int* in_sizes, int n_in,
                              void* d_out, int out_size, void* d_ws, size_t ws_size,
                              hipStream_t stream) {
    const float* text     = (const float*)d_in[0];   // [8,512,1024]
    const float* features = (const float*)d_in[1];   // [8,1024,1024]
    const float* W_q      = (const float*)d_in[2];
    const float* b_q      = (const float*)d_in[3];
    const float* W_k      = (const float*)d_in[4];
    const float* b_k      = (const float*)d_in[5];
    const float* W_o      = (const float*)d_in[6];
    const float* b_o      = (const float*)d_in[7];
    const float* g_feat   = (const float*)d_in[8];
    const float* g_q      = (const float*)d_in[9];
    const float* g_k      = (const float*)d_in[10];

    char* ws = (char*)d_ws;
    u16*   text_bf  = (u16*)(ws + 0);            //  8 MB  [4096,1024]
    u16*   Wq_bf    = (u16*)(ws + 8388608);      //  2 MB
    u16*   Wk_bf    = (u16*)(ws + 10485760);     //  2 MB
    u16*   Wo_bf    = (u16*)(ws + 12582912);     //  2 MB
    u16*   feats_bf = (u16*)(ws + 14680064);     // 16 MB  [8192,1024]
    u16*   Vt       = (u16*)(ws + 31457280);     // 16 MB  [8][1024 d][1024 n]
    float* raw      = (float*)(ws + 48234496);   // 32 MB  (shared Qraw/Kraw)
    u16*   Q_bf     = (u16*)(ws + 81788928);     //  8 MB
    u16*   K_bf     = (u16*)(ws + 90177536);     // 16 MB
    u16*   attn_bf  = (u16*)(ws + 106954752);    //  8 MB

    // 1) casts to bf16
    cast_bf16_kernel<<<4096, 256, 0, stream>>>(text, text_bf, 4096 * 1024 / 4);
    cast_bf16_kernel<<<1024, 256, 0, stream>>>(W_q, Wq_bf, 1024 * 1024 / 4);
    cast_bf16_kernel<<<1024, 256, 0, stream>>>(W_k, Wk_bf, 1024 * 1024 / 4);
    cast_bf16_kernel<<<1024, 256, 0, stream>>>(W_o, Wo_bf, 1024 * 1024 / 4);

    // 2) feats = rms_norm(features, g_feat) -> bf16 ; Vt = transpose(feats)
    rmsnorm_kernel<<<8192, 256, 0, stream>>>(features, g_feat, feats_bf);
    transpose_kernel<<<dim3(16, 16, 8), 256, 0, stream>>>(feats_bf, Vt);

    // 3) Q = rms_norm(text@WqT + bq, g_q)
    gemm_bt_kernel<<<dim3(32, 8), 256, 0, stream>>>(text_bf, Wq_bf, b_q, raw, 4096, 1024, 1024);
    rmsnorm_kernel<<<4096, 256, 0, stream>>>(raw, g_q, Q_bf);

    // 4) K = rms_norm(feats@WkT + bk, g_k)
    gemm_bt_kernel<<<dim3(64, 8), 256, 0, stream>>>(feats_bf, Wk_bf, b_k, raw, 8192, 1024, 1024);
    rmsnorm_kernel<<<8192, 256, 0, stream>>>(raw, g_k, K_bf);

    // 5) fused attention
    attn_kernel<<<dim3(8, 16, 8), 256, 0, stream>>>(Q_bf, K_bf, Vt, attn_bf);

    // 6) out = attn @ WoT + bo  (fp32 to d_out)
    gemm_bt_kernel<<<dim3(32, 8), 256, 0, stream>>>(attn_bf, Wo_bf, b_o, (float*)d_out, 4096, 1024, 1024);
}

// Round 2
// 291.647 us; speedup vs baseline: 1.1903x; 1.1903x over previous
//
#include <hip/hip_runtime.h>
#include <hip/hip_bf16.h>

// ---------------------------------------------------------------------------
// CrossAttention on MI355X (gfx950)  — v2: LDS-staged flash attention
// ---------------------------------------------------------------------------

typedef unsigned short u16;
typedef __bf16 bf16x8 __attribute__((ext_vector_type(8)));
typedef float f32x4 __attribute__((ext_vector_type(4)));

__device__ inline f32x4 mfma16(bf16x8 a, bf16x8 b, f32x4 c) {
    return __builtin_amdgcn_mfma_f32_16x16x32_bf16(a, b, c, 0, 0, 0);
}

// round-to-nearest-even f32 -> bf16 (bit pattern)
__device__ inline u16 f2bf(float f) {
    union { float f; unsigned u; } v; v.f = f;
    unsigned r = v.u + 0x7fffu + ((v.u >> 16) & 1u);
    return (u16)(r >> 16);
}

// async global->LDS, 16B per lane. LDS dest = wave-uniform base + lane*16.
__device__ inline void load_lds16(const void* g, void* l) {
    __builtin_amdgcn_global_load_lds(
        (const __attribute__((address_space(1))) void*)g,
        (__attribute__((address_space(3))) void*)l, 16, 0, 0);
}

// ---------------------------------------------------------------------------
__global__ __launch_bounds__(256) void cast_bf16_kernel(const float* __restrict__ in,
                                                        u16* __restrict__ out, int n4) {
    int i = blockIdx.x * 256 + threadIdx.x;
    if (i >= n4) return;
    float4 v = ((const float4*)in)[i];
    union { u16 s[4]; uint2 v; } p;
    p.s[0] = f2bf(v.x); p.s[1] = f2bf(v.y); p.s[2] = f2bf(v.z); p.s[3] = f2bf(v.w);
    ((uint2*)out)[i] = p.v;
}

// ---------------------------------------------------------------------------
__global__ __launch_bounds__(256) void rmsnorm_kernel(const float* __restrict__ in,
                                                      const float* __restrict__ g,
                                                      u16* __restrict__ out) {
    int row = blockIdx.x, tid = threadIdx.x;
    const float4* rp = (const float4*)(in + (size_t)row * 1024);
    float4 v = rp[tid];
    float ss = v.x * v.x + v.y * v.y + v.z * v.z + v.w * v.w;
    #pragma unroll
    for (int m = 1; m < 64; m <<= 1) ss += __shfl_xor(ss, m, 64);
    __shared__ float ws[4];
    if ((tid & 63) == 0) ws[tid >> 6] = ss;
    __syncthreads();
    float total = ws[0] + ws[1] + ws[2] + ws[3];
    float rs = rsqrtf(total * (1.0f / 1024.0f) + 1e-6f);
    float4 gv = ((const float4*)g)[tid];
    union { u16 s[4]; uint2 v; } p;
    p.s[0] = f2bf(v.x * rs * gv.x); p.s[1] = f2bf(v.y * rs * gv.y);
    p.s[2] = f2bf(v.z * rs * gv.z); p.s[3] = f2bf(v.w * rs * gv.w);
    ((uint2*)(out + (size_t)row * 1024))[tid] = p.v;
}

// ---------------------------------------------------------------------------
__global__ __launch_bounds__(256) void transpose_kernel(const u16* __restrict__ in,
                                                        u16* __restrict__ out) {
    __shared__ __align__(16) u16 tile[64][72];
    int tid = threadIdx.x, b = blockIdx.z;
    int n0 = blockIdx.x * 64, d0 = blockIdx.y * 64;
    int r = tid >> 2, cs = (tid & 3) * 16;
    const u16* src = in + ((size_t)(b * 1024 + n0 + r)) * 1024 + d0 + cs;
    union { u16 s[8]; uint4 v; } a0, a1;
    a0.v = *(const uint4*)src;
    a1.v = *(const uint4*)(src + 8);
    #pragma unroll
    for (int i = 0; i < 8; ++i) { tile[r][cs + i] = a0.s[i]; tile[r][cs + 8 + i] = a1.s[i]; }
    __syncthreads();
    union { u16 s[8]; uint4 v; } b0, b1;
    #pragma unroll
    for (int i = 0; i < 8; ++i) { b0.s[i] = tile[cs + i][r]; b1.s[i] = tile[cs + 8 + i][r]; }
    u16* dst = out + ((size_t)(b * 1024 + d0 + r)) * 1024 + n0 + cs;
    *(uint4*)dst = b0.v;
    *(uint4*)(dst + 8) = b1.v;
}

// ---------------------------------------------------------------------------
// GEMM: C[M,N] = A[M,K] * B[N,K]^T + bias[N], bf16 in, fp32 out. (m97 recipe)
__global__ __launch_bounds__(256) void gemm_bt_kernel(const u16* __restrict__ A,
                                                      const u16* __restrict__ B,
                                                      const float* __restrict__ bias,
                                                      float* __restrict__ C,
                                                      int M, int N, int K) {
    __shared__ __align__(16) u16 As[128 * 32];
    __shared__ __align__(16) u16 Bs[128 * 32];
    int tid = threadIdx.x, wave = tid >> 6, lane = tid & 63;
    int quad = lane >> 4, l15 = lane & 15;
    int wm = wave & 1, wn = wave >> 1;
    int m_blk = blockIdx.x * 128, n_blk = blockIdx.y * 128;

    f32x4 acc[4][4] = {};

    for (int k0 = 0; k0 < K; k0 += 32) {
        #pragma unroll
        for (int j = 0; j < 2; ++j) {
            int idx = j * 256 + tid;
            int row = idx >> 2, kc = (idx & 3) * 8;
            load_lds16(A + (size_t)(m_blk + row) * K + k0 + kc, As + (j * 256 + wave * 64) * 8);
            load_lds16(B + (size_t)(n_blk + row) * K + k0 + kc, Bs + (j * 256 + wave * 64) * 8);
        }
        __syncthreads();
        bf16x8 af[4], bfr[4];
        #pragma unroll
        for (int t = 0; t < 4; ++t) {
            af[t]  = *(const bf16x8*)&As[(wm * 64 + t * 16 + l15) * 32 + quad * 8];
            bfr[t] = *(const bf16x8*)&Bs[(wn * 64 + t * 16 + l15) * 32 + quad * 8];
        }
        #pragma unroll
        for (int mt = 0; mt < 4; ++mt)
            #pragma unroll
            for (int nt = 0; nt < 4; ++nt)
                acc[mt][nt] = mfma16(af[mt], bfr[nt], acc[mt][nt]);
        __syncthreads();
    }
    #pragma unroll
    for (int nt = 0; nt < 4; ++nt) {
        int col = n_blk + wn * 64 + nt * 16 + l15;
        float bv = bias[col];
        #pragma unroll
        for (int mt = 0; mt < 4; ++mt) {
            int row0 = m_blk + wm * 64 + mt * 16 + quad * 4;
            #pragma unroll
            for (int r = 0; r < 4; ++r)
                C[(size_t)(row0 + r) * N + col] = acc[mt][nt][r] + bv;
        }
    }
}

// ---------------------------------------------------------------------------
// Fused flash attention v2. Grid (qt=8, h=16, b=8), block 256 = 4 waves.
// Per iter (128 n): cooperatively stage K-tile[128n x 64d] and V-tile[64d x 128n]
// into LDS via global_load_lds (XOR-swizzled source chunks -> bank-balanced
// fragment reads). Row-sum of P via ones-column MFMA (no sum shuffles).
__global__ __launch_bounds__(256) void attn_kernel(const u16* __restrict__ Q,
                                                   const u16* __restrict__ K,
                                                   const u16* __restrict__ Vt,
                                                   u16* __restrict__ Out) {
    int b = blockIdx.z, h = blockIdx.y, qt = blockIdx.x;
    int tid = threadIdx.x, wave = tid >> 6, lane = tid & 63;
    int quad = lane >> 4, l15 = lane & 15;

    __shared__ __align__(16) u16 Ks[128 * 64];      // [n][d], chunks XOR-swizzled
    __shared__ __align__(16) u16 Vs[64 * 128];      // [d][n], chunks XOR-swizzled
    __shared__ __align__(16) u16 Plds[4][16 * 136]; // per-wave P strip, 16B-mult stride
    u16* Pw = &Plds[wave][0];

    // Q A-fragments: A[m=l15][k=quad*8+j] (+32 for second half of Hd=64)
    const size_t qoff = ((size_t)(b * 512 + qt * 64 + wave * 16 + l15)) * 1024 + h * 64 + quad * 8;
    bf16x8 qf0 = *(const bf16x8*)(Q + qoff);
    bf16x8 qf1 = *(const bf16x8*)(Q + qoff + 32);

    // staging lane decompositions
    int krl = lane >> 3, kcl = lane & 7;            // K: 8 rows x 8 chunks per inst
    int vrl = lane >> 4, vcl = lane & 15;           // V: 4 rows x 16 chunks per inst
    const u16* Kbase = K + ((size_t)(b * 1024)) * 1024 + h * 64;
    const u16* Vbase = Vt + ((size_t)(b * 1024 + h * 64)) * 1024;

    // ones B-fragment for row-sum MFMA
    __bf16 onev = (__bf16)1.0f;
    bf16x8 ones = {onev, onev, onev, onev, onev, onev, onev, onev};

    f32x4 o[4] = {};
    f32x4 lac = {0.0f, 0.0f, 0.0f, 0.0f};
    float m_t[4];
    #pragma unroll
    for (int r = 0; r < 4; ++r) m_t[r] = -1e30f;
    const float SCALE = 0.18033688011112043f;  // 0.125 * log2(e)

    for (int n0 = 0; n0 < 1024; n0 += 128) {
        // ---- stage K[128][64] and V[64][128] (XOR-swizzled source chunks)
        #pragma unroll
        for (int j = 0; j < 4; ++j) {
            int krow = wave * 32 + j * 8 + krl;                 // 0..127
            load_lds16(Kbase + (size_t)(n0 + krow) * 1024 + (kcl ^ krl) * 8,
                       Ks + (wave * 32 + j * 8) * 64);
            int vrow = wave * 16 + j * 4 + vrl;                 // 0..63 (d)
            load_lds16(Vbase + (size_t)vrow * 1024 + n0 + (vcl ^ (vrow & 7)) * 8,
                       Vs + (wave * 16 + j * 4) * 128);
        }
        __syncthreads();

        // ---- S = Q.K^T (8 n-tiles of 16), in log2-scale units
        f32x4 s[8];
        #pragma unroll
        for (int nt = 0; nt < 8; ++nt) {
            int R = nt * 16 + l15;
            int c1 = (quad ^ (l15 & 7)) * 8;
            bf16x8 kf0 = *(const bf16x8*)&Ks[R * 64 + c1];
            bf16x8 kf1 = *(const bf16x8*)&Ks[R * 64 + (c1 ^ 32)];
            f32x4 z = {0.0f, 0.0f, 0.0f, 0.0f};
            s[nt] = mfma16(qf0, kf0, z);
            s[nt] = mfma16(qf1, kf1, s[nt]);
        }
        #pragma unroll
        for (int nt = 0; nt < 8; ++nt)
            #pragma unroll
            for (int r = 0; r < 4; ++r) s[nt][r] *= SCALE;

        // ---- online max (only reduction with shuffles)
        float alpha[4];
        #pragma unroll
        for (int r = 0; r < 4; ++r) {
            float mx = s[0][r];
            #pragma unroll
            for (int nt = 1; nt < 8; ++nt) mx = fmaxf(mx, s[nt][r]);
            mx = fmaxf(mx, __shfl_xor(mx, 1, 64));
            mx = fmaxf(mx, __shfl_xor(mx, 2, 64));
            mx = fmaxf(mx, __shfl_xor(mx, 4, 64));
            mx = fmaxf(mx, __shfl_xor(mx, 8, 64));
            float mnew = fmaxf(m_t[r], mx);
            alpha[r] = exp2f(m_t[r] - mnew);
            m_t[r] = mnew;
        }

        // ---- P = 2^(s - m), bf16 into LDS strip (wave-private)
        #pragma unroll
        for (int nt = 0; nt < 8; ++nt)
            #pragma unroll
            for (int r = 0; r < 4; ++r) {
                float p = exp2f(s[nt][r] - m_t[r]);
                Pw[(quad * 4 + r) * 136 + nt * 16 + l15] = f2bf(p);
            }

        // ---- rescale running O and l
        #pragma unroll
        for (int dt = 0; dt < 4; ++dt)
            #pragma unroll
            for (int r = 0; r < 4; ++r) o[dt][r] *= alpha[r];
        #pragma unroll
        for (int r = 0; r < 4; ++r) lac[r] *= alpha[r];

        // ---- PV + ones-column row-sum
        bf16x8 pf[4];
        #pragma unroll
        for (int kc = 0; kc < 4; ++kc)
            pf[kc] = *(const bf16x8*)&Pw[l15 * 136 + kc * 32 + quad * 8];
        #pragma unroll
        for (int kc = 0; kc < 4; ++kc) {
            lac = mfma16(pf[kc], ones, lac);
            #pragma unroll
            for (int dt = 0; dt < 4; ++dt) {
                int d = dt * 16 + l15;
                int ch = ((kc * 4 + quad) ^ (l15 & 7)) * 8;
                bf16x8 vf = *(const bf16x8*)&Vs[d * 128 + ch];
                o[dt] = mfma16(pf[kc], vf, o[dt]);
            }
        }
        __syncthreads();
    }

    // ---- epilogue: O /= l (l already per-lane in C-layout), write bf16
    #pragma unroll
    for (int r = 0; r < 4; ++r) lac[r] = 1.0f / lac[r];
    #pragma unroll
    for (int dt = 0; dt < 4; ++dt)
        #pragma unroll
        for (int r = 0; r < 4; ++r) {
            size_t oi = ((size_t)(b * 512 + qt * 64 + wave * 16 + quad * 4 + r)) * 1024
                        + h * 64 + dt * 16 + l15;
            Out[oi] = f2bf(o[dt][r] * lac[r]);
        }
}

// ---------------------------------------------------------------------------
extern "C" void kernel_launch(void* const* d_in, const int* in_sizes, int n_in,
                              void* d_out, int out_size, void* d_ws, size_t ws_size,
                              hipStream_t stream) {
    const float* text     = (const float*)d_in[0];   // [8,512,1024]
    const float* features = (const float*)d_in[1];   // [8,1024,1024]
    const float* W_q      = (const float*)d_in[2];
    const float* b_q      = (const float*)d_in[3];
    const float* W_k      = (const float*)d_in[4];
    const float* b_k      = (const float*)d_in[5];
    const float* W_o      = (const float*)d_in[6];
    const float* b_o      = (const float*)d_in[7];
    const float* g_feat   = (const float*)d_in[8];
    const float* g_q      = (const float*)d_in[9];
    const float* g_k      = (const float*)d_in[10];

    char* ws = (char*)d_ws;
    u16*   text_bf  = (u16*)(ws + 0);            //  8 MB  [4096,1024]
    u16*   Wq_bf    = (u16*)(ws + 8388608);      //  2 MB
    u16*   Wk_bf    = (u16*)(ws + 10485760);     //  2 MB
    u16*   Wo_bf    = (u16*)(ws + 12582912);     //  2 MB
    u16*   feats_bf = (u16*)(ws + 14680064);     // 16 MB  [8192,1024]
    u16*   Vt       = (u16*)(ws + 31457280);     // 16 MB  [8][1024 d][1024 n]
    float* raw      = (float*)(ws + 48234496);   // 32 MB  (shared Qraw/Kraw)
    u16*   Q_bf     = (u16*)(ws + 81788928);     //  8 MB
    u16*   K_bf     = (u16*)(ws + 90177536);     // 16 MB
    u16*   attn_bf  = (u16*)(ws + 106954752);    //  8 MB

    cast_bf16_kernel<<<4096, 256, 0, stream>>>(text, text_bf, 4096 * 1024 / 4);
    cast_bf16_kernel<<<1024, 256, 0, stream>>>(W_q, Wq_bf, 1024 * 1024 / 4);
    cast_bf16_kernel<<<1024, 256, 0, stream>>>(W_k, Wk_bf, 1024 * 1024 / 4);
    cast_bf16_kernel<<<1024, 256, 0, stream>>>(W_o, Wo_bf, 1024 * 1024 / 4);

    rmsnorm_kernel<<<8192, 256, 0, stream>>>(features, g_feat, feats_bf);
    transpose_kernel<<<dim3(16, 16, 8), 256, 0, stream>>>(feats_bf, Vt);

    gemm_bt_kernel<<<dim3(32, 8), 256, 0, stream>>>(text_bf, Wq_bf, b_q, raw, 4096, 1024, 1024);
    rmsnorm_kernel<<<4096, 256, 0, stream>>>(raw, g_q, Q_bf);

    gemm_bt_kernel<<<dim3(64, 8), 256, 0, stream>>>(feats_bf, Wk_bf, b_k, raw, 8192, 1024, 1024);
    rmsnorm_kernel<<<8192, 256, 0, stream>>>(raw, g_k, K_bf);

    attn_kernel<<<dim3(8, 16, 8), 256, 0, stream>>>(Q_bf, K_bf, Vt, attn_bf);

    gemm_bt_kernel<<<dim3(32, 8), 256, 0, stream>>>(attn_bf, Wo_bf, b_o, (float*)d_out, 4096, 1024, 1024);
}

// Round 3
// 275.918 us; speedup vs baseline: 1.2581x; 1.0570x over previous
//
#include <hip/hip_runtime.h>
#include <hip/hip_bf16.h>

// ---------------------------------------------------------------------------
// CrossAttention on MI355X (gfx950) — v3: S^T flash attention, fixed-max
// softmax (exp2-domain), packed P LDS traffic, XCD-local K/V reuse.
// ---------------------------------------------------------------------------

typedef unsigned short u16;
typedef __bf16 bf16x8 __attribute__((ext_vector_type(8)));
typedef float f32x4 __attribute__((ext_vector_type(4)));

__device__ inline f32x4 mfma16(bf16x8 a, bf16x8 b, f32x4 c) {
    return __builtin_amdgcn_mfma_f32_16x16x32_bf16(a, b, c, 0, 0, 0);
}

// round-to-nearest-even f32 -> bf16 (bit pattern)
__device__ inline u16 f2bf(float f) {
    union { float f; unsigned u; } v; v.f = f;
    unsigned r = v.u + 0x7fffu + ((v.u >> 16) & 1u);
    return (u16)(r >> 16);
}

// pack two f32 -> two bf16 in one u32 (round-half-up: add + v_perm)
__device__ inline unsigned pk_bf16(float a, float b) {
    union { float f; unsigned u; } x, y; x.f = a; y.f = b;
    return __builtin_amdgcn_perm(y.u + 0x8000u, x.u + 0x8000u, 0x07060302u);
}

// async global->LDS, 16B per lane. LDS dest = wave-uniform base + lane*16.
__device__ inline void load_lds16(const void* g, void* l) {
    __builtin_amdgcn_global_load_lds(
        (const __attribute__((address_space(1))) void*)g,
        (__attribute__((address_space(3))) void*)l, 16, 0, 0);
}

// ---------------------------------------------------------------------------
__global__ __launch_bounds__(256) void cast_bf16_kernel(const float* __restrict__ in,
                                                        u16* __restrict__ out, int n4) {
    int i = blockIdx.x * 256 + threadIdx.x;
    if (i >= n4) return;
    float4 v = ((const float4*)in)[i];
    union { u16 s[4]; uint2 v; } p;
    p.s[0] = f2bf(v.x); p.s[1] = f2bf(v.y); p.s[2] = f2bf(v.z); p.s[3] = f2bf(v.w);
    ((uint2*)out)[i] = p.v;
}

// ---------------------------------------------------------------------------
// RMSNorm (last dim 1024), fp32 in, bf16 out, extra constant output scale.
__global__ __launch_bounds__(256) void rmsnorm_kernel(const float* __restrict__ in,
                                                      const float* __restrict__ g,
                                                      u16* __restrict__ out, float scale) {
    int row = blockIdx.x, tid = threadIdx.x;
    const float4* rp = (const float4*)(in + (size_t)row * 1024);
    float4 v = rp[tid];
    float ss = v.x * v.x + v.y * v.y + v.z * v.z + v.w * v.w;
    #pragma unroll
    for (int m = 1; m < 64; m <<= 1) ss += __shfl_xor(ss, m, 64);
    __shared__ float ws[4];
    if ((tid & 63) == 0) ws[tid >> 6] = ss;
    __syncthreads();
    float total = ws[0] + ws[1] + ws[2] + ws[3];
    float rs = rsqrtf(total * (1.0f / 1024.0f) + 1e-6f) * scale;
    float4 gv = ((const float4*)g)[tid];
    union { u16 s[4]; uint2 v; } p;
    p.s[0] = f2bf(v.x * rs * gv.x); p.s[1] = f2bf(v.y * rs * gv.y);
    p.s[2] = f2bf(v.z * rs * gv.z); p.s[3] = f2bf(v.w * rs * gv.w);
    ((uint2*)(out + (size_t)row * 1024))[tid] = p.v;
}

// ---------------------------------------------------------------------------
__global__ __launch_bounds__(256) void transpose_kernel(const u16* __restrict__ in,
                                                        u16* __restrict__ out) {
    __shared__ __align__(16) u16 tile[64][72];
    int tid = threadIdx.x, b = blockIdx.z;
    int n0 = blockIdx.x * 64, d0 = blockIdx.y * 64;
    int r = tid >> 2, cs = (tid & 3) * 16;
    const u16* src = in + ((size_t)(b * 1024 + n0 + r)) * 1024 + d0 + cs;
    union { u16 s[8]; uint4 v; } a0, a1;
    a0.v = *(const uint4*)src;
    a1.v = *(const uint4*)(src + 8);
    #pragma unroll
    for (int i = 0; i < 8; ++i) { tile[r][cs + i] = a0.s[i]; tile[r][cs + 8 + i] = a1.s[i]; }
    __syncthreads();
    union { u16 s[8]; uint4 v; } b0, b1;
    #pragma unroll
    for (int i = 0; i < 8; ++i) { b0.s[i] = tile[cs + i][r]; b1.s[i] = tile[cs + 8 + i][r]; }
    u16* dst = out + ((size_t)(b * 1024 + d0 + r)) * 1024 + n0 + cs;
    *(uint4*)dst = b0.v;
    *(uint4*)(dst + 8) = b1.v;
}

// ---------------------------------------------------------------------------
// GEMM: C[M,N] = A[M,K] * B[N,K]^T + bias[N], bf16 in, fp32 out. (m97 recipe)
__global__ __launch_bounds__(256) void gemm_bt_kernel(const u16* __restrict__ A,
                                                      const u16* __restrict__ B,
                                                      const float* __restrict__ bias,
                                                      float* __restrict__ C,
                                                      int M, int N, int K) {
    __shared__ __align__(16) u16 As[128 * 32];
    __shared__ __align__(16) u16 Bs[128 * 32];
    int tid = threadIdx.x, wave = tid >> 6, lane = tid & 63;
    int quad = lane >> 4, l15 = lane & 15;
    int wm = wave & 1, wn = wave >> 1;
    int m_blk = blockIdx.x * 128, n_blk = blockIdx.y * 128;

    f32x4 acc[4][4] = {};

    for (int k0 = 0; k0 < K; k0 += 32) {
        #pragma unroll
        for (int j = 0; j < 2; ++j) {
            int idx = j * 256 + tid;
            int row = idx >> 2, kc = (idx & 3) * 8;
            load_lds16(A + (size_t)(m_blk + row) * K + k0 + kc, As + (j * 256 + wave * 64) * 8);
            load_lds16(B + (size_t)(n_blk + row) * K + k0 + kc, Bs + (j * 256 + wave * 64) * 8);
        }
        __syncthreads();
        bf16x8 af[4], bfr[4];
        #pragma unroll
        for (int t = 0; t < 4; ++t) {
            af[t]  = *(const bf16x8*)&As[(wm * 64 + t * 16 + l15) * 32 + quad * 8];
            bfr[t] = *(const bf16x8*)&Bs[(wn * 64 + t * 16 + l15) * 32 + quad * 8];
        }
        #pragma unroll
        for (int mt = 0; mt < 4; ++mt)
            #pragma unroll
            for (int nt = 0; nt < 4; ++nt)
                acc[mt][nt] = mfma16(af[mt], bfr[nt], acc[mt][nt]);
        __syncthreads();
    }
    #pragma unroll
    for (int nt = 0; nt < 4; ++nt) {
        int col = n_blk + wn * 64 + nt * 16 + l15;
        float bv = bias[col];
        #pragma unroll
        for (int mt = 0; mt < 4; ++mt) {
            int row0 = m_blk + wm * 64 + mt * 16 + quad * 4;
            #pragma unroll
            for (int r = 0; r < 4; ++r)
                C[(size_t)(row0 + r) * N + col] = acc[mt][nt][r] + bv;
        }
    }
}

// ---------------------------------------------------------------------------
// Flash attention v3. Grid (bh=128, qt=8), block 256 = 4 waves, 16 Q rows/wave.
// S^T = K.Q^T via MFMA(A=K,B=Q), C-init = -16 (fixed softmax max, exp2 domain;
// Q pre-scaled by 0.125*log2e). P packed to LDS with b64 writes (n contiguous
// in quad*4+r). PV: O^T = MFMA(A=V^T, B=P); row-sum l via ones-A MFMA.
__global__ __launch_bounds__(256) void attn_kernel(const u16* __restrict__ Q,
                                                   const u16* __restrict__ K,
                                                   const u16* __restrict__ Vt,
                                                   u16* __restrict__ Out) {
    int bh = blockIdx.x, qt = blockIdx.y;
    int b = bh >> 4, h = bh & 15;
    int tid = threadIdx.x, wave = tid >> 6, lane = tid & 63;
    int quad = lane >> 4, l15 = lane & 15;

    __shared__ __align__(16) u16 Ks[128 * 64];      // [n][d], chunks XOR-swizzled
    __shared__ __align__(16) u16 Vs[64 * 128];      // [d][n], chunks XOR-swizzled
    __shared__ __align__(16) u16 Plds[4][16 * 136]; // per-wave P [m=16][n=128], stride 136
    u16* Pw = &Plds[wave][0];

    // Q B-frag: B[m=l15][k=quad*8+j] (+32 second half of Hd=64). Pre-scaled.
    const size_t qoff = ((size_t)(b * 512 + qt * 64 + wave * 16 + l15)) * 1024 + h * 64 + quad * 8;
    bf16x8 qf0 = *(const bf16x8*)(Q + qoff);
    bf16x8 qf1 = *(const bf16x8*)(Q + qoff + 32);

    int krl = lane >> 3, kcl = lane & 7;            // K staging: 8 rows x 8 chunks
    int vrl = lane >> 4, vcl = lane & 15;           // V staging: 4 rows x 16 chunks
    const u16* Kbase = K + ((size_t)(b * 1024)) * 1024 + h * 64;
    const u16* Vbase = Vt + ((size_t)(b * 1024 + h * 64)) * 1024;

    __bf16 onev = (__bf16)1.0f;
    bf16x8 ones = {onev, onev, onev, onev, onev, onev, onev, onev};

    f32x4 o[4] = {};                          // o[dt] = O^T[d=dt*16+quad*4+r][m=l15]
    f32x4 lac = {0.0f, 0.0f, 0.0f, 0.0f};    // l[m=l15] in every slot

    for (int n0 = 0; n0 < 1024; n0 += 128) {
        // ---- stage K[128][64] and V[64][128] (XOR-swizzled source chunks)
        #pragma unroll
        for (int j = 0; j < 4; ++j) {
            int krow = wave * 32 + j * 8 + krl;
            load_lds16(Kbase + (size_t)(n0 + krow) * 1024 + (kcl ^ krl) * 8,
                       Ks + (wave * 32 + j * 8) * 64);
            int vrow = wave * 16 + j * 4 + vrl;
            load_lds16(Vbase + (size_t)vrow * 1024 + n0 + (vcl ^ (vrow & 7)) * 8,
                       Vs + (wave * 16 + j * 4) * 128);
        }
        __syncthreads();

        // ---- S^T tiles (8 x 16n), C-init -16 = fixed softmax max (log2 units)
        f32x4 s[8];
        #pragma unroll
        for (int nt = 0; nt < 8; ++nt) {
            int R = nt * 16 + l15;
            int c1 = (quad ^ (l15 & 7)) * 8;
            bf16x8 kf0 = *(const bf16x8*)&Ks[R * 64 + c1];
            bf16x8 kf1 = *(const bf16x8*)&Ks[R * 64 + (c1 ^ 32)];
            f32x4 z = {-16.0f, -16.0f, -16.0f, -16.0f};
            s[nt] = mfma16(kf0, qf0, z);
            s[nt] = mfma16(kf1, qf1, s[nt]);
        }

        // ---- P = 2^(s-16): exp2, pack pairs, b64 write (n = nt*16+quad*4+r)
        #pragma unroll
        for (int nt = 0; nt < 8; ++nt) {
            float p0 = exp2f(s[nt][0]), p1 = exp2f(s[nt][1]);
            float p2 = exp2f(s[nt][2]), p3 = exp2f(s[nt][3]);
            uint2 pk; pk.x = pk_bf16(p0, p1); pk.y = pk_bf16(p2, p3);
            *(uint2*)&Pw[l15 * 136 + nt * 16 + quad * 4] = pk;
        }

        // ---- PV: O^T += V^T . P^T ; l += ones . P^T (wave-private P, no barrier)
        bf16x8 pf[4];
        #pragma unroll
        for (int kc = 0; kc < 4; ++kc)
            pf[kc] = *(const bf16x8*)&Pw[l15 * 136 + kc * 32 + quad * 8];
        #pragma unroll
        for (int kc = 0; kc < 4; ++kc) {
            lac = mfma16(ones, pf[kc], lac);
            #pragma unroll
            for (int dt = 0; dt < 4; ++dt) {
                int d = dt * 16 + l15;
                int ch = ((kc * 4 + quad) ^ (l15 & 7)) * 8;
                bf16x8 vf = *(const bf16x8*)&Vs[d * 128 + ch];
                o[dt] = mfma16(vf, pf[kc], o[dt]);
            }
        }
        __syncthreads();
    }

    // ---- epilogue: O[m][d] = O^T/l, 4 consecutive d per lane -> b64 stores
    float il = 1.0f / lac[0];
    size_t obase = ((size_t)(b * 512 + qt * 64 + wave * 16 + l15)) * 1024 + h * 64 + quad * 4;
    #pragma unroll
    for (int dt = 0; dt < 4; ++dt) {
        uint2 pk;
        pk.x = pk_bf16(o[dt][0] * il, o[dt][1] * il);
        pk.y = pk_bf16(o[dt][2] * il, o[dt][3] * il);
        *(uint2*)(Out + obase + dt * 16) = pk;
    }
}

// ---------------------------------------------------------------------------
extern "C" void kernel_launch(void* const* d_in, const int* in_sizes, int n_in,
                              void* d_out, int out_size, void* d_ws, size_t ws_size,
                              hipStream_t stream) {
    const float* text     = (const float*)d_in[0];
    const float* features = (const float*)d_in[1];
    const float* W_q      = (const float*)d_in[2];
    const float* b_q      = (const float*)d_in[3];
    const float* W_k      = (const float*)d_in[4];
    const float* b_k      = (const float*)d_in[5];
    const float* W_o      = (const float*)d_in[6];
    const float* b_o      = (const float*)d_in[7];
    const float* g_feat   = (const float*)d_in[8];
    const float* g_q      = (const float*)d_in[9];
    const float* g_k      = (const float*)d_in[10];

    char* ws = (char*)d_ws;
    u16*   text_bf  = (u16*)(ws + 0);            //  8 MB
    u16*   Wq_bf    = (u16*)(ws + 8388608);      //  2 MB
    u16*   Wk_bf    = (u16*)(ws + 10485760);     //  2 MB
    u16*   Wo_bf    = (u16*)(ws + 12582912);     //  2 MB
    u16*   feats_bf = (u16*)(ws + 14680064);     // 16 MB
    u16*   Vt       = (u16*)(ws + 31457280);     // 16 MB [8][1024 d][1024 n]
    float* raw      = (float*)(ws + 48234496);   // 32 MB
    u16*   Q_bf     = (u16*)(ws + 81788928);     //  8 MB
    u16*   K_bf     = (u16*)(ws + 90177536);     // 16 MB
    u16*   attn_bf  = (u16*)(ws + 106954752);    //  8 MB

    const float QSCALE = 0.18033688011112042f;   // 0.125 * log2(e)

    cast_bf16_kernel<<<4096, 256, 0, stream>>>(text, text_bf, 4096 * 1024 / 4);
    cast_bf16_kernel<<<1024, 256, 0, stream>>>(W_q, Wq_bf, 1024 * 1024 / 4);
    cast_bf16_kernel<<<1024, 256, 0, stream>>>(W_k, Wk_bf, 1024 * 1024 / 4);
    cast_bf16_kernel<<<1024, 256, 0, stream>>>(W_o, Wo_bf, 1024 * 1024 / 4);

    rmsnorm_kernel<<<8192, 256, 0, stream>>>(features, g_feat, feats_bf, 1.0f);
    transpose_kernel<<<dim3(16, 16, 8), 256, 0, stream>>>(feats_bf, Vt);

    gemm_bt_kernel<<<dim3(32, 8), 256, 0, stream>>>(text_bf, Wq_bf, b_q, raw, 4096, 1024, 1024);
    rmsnorm_kernel<<<4096, 256, 0, stream>>>(raw, g_q, Q_bf, QSCALE);

    gemm_bt_kernel<<<dim3(64, 8), 256, 0, stream>>>(feats_bf, Wk_bf, b_k, raw, 8192, 1024, 1024);
    rmsnorm_kernel<<<8192, 256, 0, stream>>>(raw, g_k, K_bf, 1.0f);

    attn_kernel<<<dim3(128, 8), 256, 0, stream>>>(Q_bf, K_bf, Vt, attn_bf);

    gemm_bt_kernel<<<dim3(32, 8), 256, 0, stream>>>(attn_bf, Wo_bf, b_o, (float*)d_out, 4096, 1024, 1024);
}

// Round 4
// 237.745 us; speedup vs baseline: 1.4601x; 1.1606x over previous
//
#include <hip/hip_runtime.h>
#include <hip/hip_bf16.h>

// ---------------------------------------------------------------------------
// CrossAttention on MI355X (gfx950) — v4: merged 128x64-tile GEMMs (6 blk/CU),
// bf16 in-place RMSNorm, 64-chunk attention (25.6KB LDS -> full co-residency),
// fused casts. 7 launches total.
// ---------------------------------------------------------------------------

typedef unsigned short u16;
typedef __bf16 bf16x8 __attribute__((ext_vector_type(8)));
typedef float f32x4 __attribute__((ext_vector_type(4)));

__device__ inline f32x4 mfma16(bf16x8 a, bf16x8 b, f32x4 c) {
    return __builtin_amdgcn_mfma_f32_16x16x32_bf16(a, b, c, 0, 0, 0);
}

__device__ inline u16 f2bf(float f) {
    union { float f; unsigned u; } v; v.f = f;
    unsigned r = v.u + 0x7fffu + ((v.u >> 16) & 1u);
    return (u16)(r >> 16);
}

__device__ inline float bf2f(u16 x) {
    union { unsigned u; float f; } v; v.u = ((unsigned)x) << 16; return v.f;
}

// pack two f32 -> two bf16 in one u32 (round: add 0x8000 + v_perm)
__device__ inline unsigned pk_bf16(float a, float b) {
    union { float f; unsigned u; } x, y; x.f = a; y.f = b;
    return __builtin_amdgcn_perm(y.u + 0x8000u, x.u + 0x8000u, 0x07060302u);
}

__device__ inline void load_lds16(const void* g, void* l) {
    __builtin_amdgcn_global_load_lds(
        (const __attribute__((address_space(1))) void*)g,
        (__attribute__((address_space(3))) void*)l, 16, 0, 0);
}

// ---------------------------------------------------------------------------
// fused cast: text (1048576 f4) + Wq + Wk + Wo (262144 f4 each)
__global__ __launch_bounds__(256) void cast4_kernel(const float* __restrict__ text,
                                                    const float* __restrict__ Wq,
                                                    const float* __restrict__ Wk,
                                                    const float* __restrict__ Wo,
                                                    u16* __restrict__ otext, u16* __restrict__ oWq,
                                                    u16* __restrict__ oWk, u16* __restrict__ oWo) {
    int i = blockIdx.x * 256 + threadIdx.x;
    const float* src; u16* dst; int off;
    if (i < 1048576)      { src = text; dst = otext; off = i; }
    else if (i < 1310720) { src = Wq;   dst = oWq;   off = i - 1048576; }
    else if (i < 1572864) { src = Wk;   dst = oWk;   off = i - 1310720; }
    else                  { src = Wo;   dst = oWo;   off = i - 1572864; }
    float4 v = ((const float4*)src)[off];
    uint2 p; p.x = pk_bf16(v.x, v.y); p.y = pk_bf16(v.z, v.w);
    ((uint2*)dst)[off] = p;
}

// ---------------------------------------------------------------------------
// RMSNorm (last dim 1024), fp32 in, bf16 out, constant output scale.
__global__ __launch_bounds__(256) void rmsnorm_kernel(const float* __restrict__ in,
                                                      const float* __restrict__ g,
                                                      u16* __restrict__ out, float scale) {
    int row = blockIdx.x, tid = threadIdx.x;
    float4 v = ((const float4*)(in + (size_t)row * 1024))[tid];
    float ss = v.x * v.x + v.y * v.y + v.z * v.z + v.w * v.w;
    #pragma unroll
    for (int m = 1; m < 64; m <<= 1) ss += __shfl_xor(ss, m, 64);
    __shared__ float ws[4];
    if ((tid & 63) == 0) ws[tid >> 6] = ss;
    __syncthreads();
    float rs = rsqrtf((ws[0] + ws[1] + ws[2] + ws[3]) * (1.0f / 1024.0f) + 1e-6f) * scale;
    float4 gv = ((const float4*)g)[tid];
    uint2 p;
    p.x = pk_bf16(v.x * rs * gv.x, v.y * rs * gv.y);
    p.y = pk_bf16(v.z * rs * gv.z, v.w * rs * gv.w);
    ((uint2*)(out + (size_t)row * 1024))[tid] = p;
}

// ---------------------------------------------------------------------------
// In-place RMSNorm on bf16 rows: rows 0..4095 = Q (g_q, qscale), 4096.. = K (g_k).
__global__ __launch_bounds__(256) void rmsnorm_qk_kernel(u16* __restrict__ QK,
                                                         const float* __restrict__ g_q,
                                                         const float* __restrict__ g_k,
                                                         float qscale) {
    int row = blockIdx.x, tid = threadIdx.x;
    const float* g = (row < 4096) ? g_q : g_k;
    float outsc = (row < 4096) ? qscale : 1.0f;
    uint2* rp = (uint2*)(QK + (size_t)row * 1024) + tid;
    union { u16 s[4]; uint2 v; } in; in.v = *rp;
    float x0 = bf2f(in.s[0]), x1 = bf2f(in.s[1]), x2 = bf2f(in.s[2]), x3 = bf2f(in.s[3]);
    float ss = x0 * x0 + x1 * x1 + x2 * x2 + x3 * x3;
    #pragma unroll
    for (int m = 1; m < 64; m <<= 1) ss += __shfl_xor(ss, m, 64);
    __shared__ float ws[4];
    if ((tid & 63) == 0) ws[tid >> 6] = ss;
    __syncthreads();
    float rs = rsqrtf((ws[0] + ws[1] + ws[2] + ws[3]) * (1.0f / 1024.0f) + 1e-6f) * outsc;
    float4 gv = ((const float4*)g)[tid];
    uint2 p;
    p.x = pk_bf16(x0 * rs * gv.x, x1 * rs * gv.y);
    p.y = pk_bf16(x2 * rs * gv.z, x3 * rs * gv.w);
    *rp = p;
}

// ---------------------------------------------------------------------------
__global__ __launch_bounds__(256) void transpose_kernel(const u16* __restrict__ in,
                                                        u16* __restrict__ out) {
    __shared__ __align__(16) u16 tile[64][72];
    int tid = threadIdx.x, b = blockIdx.z;
    int n0 = blockIdx.x * 64, d0 = blockIdx.y * 64;
    int r = tid >> 2, cs = (tid & 3) * 16;
    const u16* src = in + ((size_t)(b * 1024 + n0 + r)) * 1024 + d0 + cs;
    union { u16 s[8]; uint4 v; } a0, a1;
    a0.v = *(const uint4*)src;
    a1.v = *(const uint4*)(src + 8);
    #pragma unroll
    for (int i = 0; i < 8; ++i) { tile[r][cs + i] = a0.s[i]; tile[r][cs + 8 + i] = a1.s[i]; }
    __syncthreads();
    union { u16 s[8]; uint4 v; } b0, b1;
    #pragma unroll
    for (int i = 0; i < 8; ++i) { b0.s[i] = tile[cs + i][r]; b1.s[i] = tile[cs + 8 + i][r]; }
    u16* dst = out + ((size_t)(b * 1024 + d0 + r)) * 1024 + n0 + cs;
    *(uint4*)dst = b0.v;
    *(uint4*)(dst + 8) = b1.v;
}

// ---------------------------------------------------------------------------
// 128x64-tile GEMM body: C[M,N] = A[M,K].B[N,K]^T + bias. 4 waves, each 64x32
// (4x2 MFMA tiles). LDS 12KB -> ~6 blocks/CU co-residency.
template <bool BF16OUT>
__device__ __forceinline__ void gemm64_tile(const u16* __restrict__ A, const u16* __restrict__ B,
                                            const float* __restrict__ bias, void* __restrict__ Cout,
                                            int m_blk, int n_blk, int K, int N,
                                            u16* As, u16* Bs) {
    int tid = threadIdx.x, wave = tid >> 6, lane = tid & 63;
    int quad = lane >> 4, l15 = lane & 15;
    int wm = wave & 1, wn = wave >> 1;

    f32x4 acc[4][2] = {};

    for (int k0 = 0; k0 < K; k0 += 32) {
        #pragma unroll
        for (int j = 0; j < 2; ++j) {
            int idx = j * 256 + tid;
            int row = idx >> 2, kc = (idx & 3) * 8;
            load_lds16(A + (size_t)(m_blk + row) * K + k0 + kc, As + (j * 256 + wave * 64) * 8);
        }
        {
            int row = tid >> 2, kc = (tid & 3) * 8;
            load_lds16(B + (size_t)(n_blk + row) * K + k0 + kc, Bs + (wave * 64) * 8);
        }
        __syncthreads();
        bf16x8 af[4], bfr[2];
        #pragma unroll
        for (int t = 0; t < 4; ++t)
            af[t] = *(const bf16x8*)&As[(wm * 64 + t * 16 + l15) * 32 + quad * 8];
        #pragma unroll
        for (int t = 0; t < 2; ++t)
            bfr[t] = *(const bf16x8*)&Bs[(wn * 32 + t * 16 + l15) * 32 + quad * 8];
        #pragma unroll
        for (int mt = 0; mt < 4; ++mt)
            #pragma unroll
            for (int nt = 0; nt < 2; ++nt)
                acc[mt][nt] = mfma16(af[mt], bfr[nt], acc[mt][nt]);
        __syncthreads();
    }
    #pragma unroll
    for (int nt = 0; nt < 2; ++nt) {
        int col = n_blk + wn * 32 + nt * 16 + l15;
        float bv = bias[col];
        #pragma unroll
        for (int mt = 0; mt < 4; ++mt) {
            int row0 = m_blk + wm * 64 + mt * 16 + quad * 4;
            #pragma unroll
            for (int r = 0; r < 4; ++r) {
                float val = acc[mt][nt][r] + bv;
                if (BF16OUT) ((u16*)Cout)[(size_t)(row0 + r) * N + col] = f2bf(val);
                else       ((float*)Cout)[(size_t)(row0 + r) * N + col] = val;
            }
        }
    }
}

// merged Q-proj (512 blocks) + K-proj (1024 blocks), bf16 out into one buffer
__global__ __launch_bounds__(256) void gemm_qk_kernel(const u16* __restrict__ text_bf,
                                                      const u16* __restrict__ Wq,
                                                      const u16* __restrict__ feats_bf,
                                                      const u16* __restrict__ Wk,
                                                      const float* __restrict__ b_q,
                                                      const float* __restrict__ b_k,
                                                      u16* __restrict__ QK) {
    __shared__ __align__(16) u16 As[128 * 32];
    __shared__ __align__(16) u16 Bs[64 * 32];
    int id = blockIdx.x;
    if (id < 512) {
        gemm64_tile<true>(text_bf, Wq, b_q, QK, (id & 31) * 128, (id >> 5) * 64, 1024, 1024, As, Bs);
    } else {
        id -= 512;
        gemm64_tile<true>(feats_bf, Wk, b_k, QK + 4096 * 1024,
                          (id & 63) * 128, (id >> 6) * 64, 1024, 1024, As, Bs);
    }
}

// O-projection, fp32 out
__global__ __launch_bounds__(256) void gemm_o_kernel(const u16* __restrict__ A,
                                                     const u16* __restrict__ B,
                                                     const float* __restrict__ bias,
                                                     float* __restrict__ C) {
    __shared__ __align__(16) u16 As[128 * 32];
    __shared__ __align__(16) u16 Bs[64 * 32];
    int id = blockIdx.x;
    gemm64_tile<false>(A, B, bias, C, (id & 31) * 128, (id >> 5) * 64, 1024, 1024, As, Bs);
}

// ---------------------------------------------------------------------------
// Flash attention v4: n-chunk 64, LDS 25.6KB (Ks 8K + Vs 8K + P 9.2K) -> grid
// 1024 blocks fully co-resident at 4 blocks/CU (6 possible). S^T = K.Q^T with
// C-init -16 (fixed max, exp2 domain; Q pre-scaled by 0.125*log2e).
__global__ __launch_bounds__(256) void attn_kernel(const u16* __restrict__ Q,
                                                   const u16* __restrict__ K,
                                                   const u16* __restrict__ Vt,
                                                   u16* __restrict__ Out) {
    int bh = blockIdx.x, qt = blockIdx.y;
    int b = bh >> 4, h = bh & 15;
    int tid = threadIdx.x, wave = tid >> 6, lane = tid & 63;
    int quad = lane >> 4, l15 = lane & 15;

    __shared__ __align__(16) u16 Ks[64 * 64];       // [n][d], chunks XOR-swizzled
    __shared__ __align__(16) u16 Vs[64 * 64];       // [d][n], chunks XOR-swizzled
    __shared__ __align__(16) u16 Plds[4][16 * 72];  // per-wave P [m=16][n=64]
    u16* Pw = &Plds[wave][0];

    const size_t qoff = ((size_t)(b * 512 + qt * 64 + wave * 16 + l15)) * 1024 + h * 64 + quad * 8;
    bf16x8 qf0 = *(const bf16x8*)(Q + qoff);
    bf16x8 qf1 = *(const bf16x8*)(Q + qoff + 32);

    int srl = lane >> 3, scl = lane & 7;            // staging: 8 rows x 8 chunks
    const u16* Kbase = K + ((size_t)(b * 1024)) * 1024 + h * 64;
    const u16* Vbase = Vt + ((size_t)(b * 1024 + h * 64)) * 1024;

    __bf16 onev = (__bf16)1.0f;
    bf16x8 ones = {onev, onev, onev, onev, onev, onev, onev, onev};

    f32x4 o[4] = {};                       // o[dt] = O^T[d=dt*16+quad*4+r][m=l15]
    f32x4 lac = {0.0f, 0.0f, 0.0f, 0.0f}; // l[m=l15]

    for (int n0 = 0; n0 < 1024; n0 += 64) {
        // ---- stage K[64][64], V[64][64] (XOR-swizzled chunks)
        #pragma unroll
        for (int j = 0; j < 2; ++j) {
            int row = wave * 16 + j * 8 + srl;
            load_lds16(Kbase + (size_t)(n0 + row) * 1024 + (scl ^ srl) * 8,
                       Ks + (wave * 16 + j * 8) * 64);
            load_lds16(Vbase + (size_t)row * 1024 + n0 + (scl ^ srl) * 8,
                       Vs + (wave * 16 + j * 8) * 64);
        }
        __syncthreads();

        // ---- S^T tiles (4 x 16n), C-init -16
        f32x4 s[4];
        #pragma unroll
        for (int nt = 0; nt < 4; ++nt) {
            int R = nt * 16 + l15;
            int c1 = (quad ^ (l15 & 7)) * 8;
            bf16x8 kf0 = *(const bf16x8*)&Ks[R * 64 + c1];
            bf16x8 kf1 = *(const bf16x8*)&Ks[R * 64 + (c1 ^ 32)];
            f32x4 z = {-16.0f, -16.0f, -16.0f, -16.0f};
            s[nt] = mfma16(kf0, qf0, z);
            s[nt] = mfma16(kf1, qf1, s[nt]);
        }

        // ---- P = 2^(s-16), packed b64 writes (n = nt*16 + quad*4 + r)
        #pragma unroll
        for (int nt = 0; nt < 4; ++nt) {
            uint2 pk;
            pk.x = pk_bf16(exp2f(s[nt][0]), exp2f(s[nt][1]));
            pk.y = pk_bf16(exp2f(s[nt][2]), exp2f(s[nt][3]));
            *(uint2*)&Pw[l15 * 72 + nt * 16 + quad * 4] = pk;
        }

        // ---- PV: O^T += V^T.P^T ; l += ones.P^T (wave-private P)
        bf16x8 pf[2];
        #pragma unroll
        for (int kc = 0; kc < 2; ++kc)
            pf[kc] = *(const bf16x8*)&Pw[l15 * 72 + kc * 32 + quad * 8];
        #pragma unroll
        for (int kc = 0; kc < 2; ++kc) {
            lac = mfma16(ones, pf[kc], lac);
            #pragma unroll
            for (int dt = 0; dt < 4; ++dt) {
                int d = dt * 16 + l15;
                int ch = ((kc * 4 + quad) ^ (l15 & 7)) * 8;
                bf16x8 vf = *(const bf16x8*)&Vs[d * 64 + ch];
                o[dt] = mfma16(vf, pf[kc], o[dt]);
            }
        }
        __syncthreads();
    }

    float il = 1.0f / lac[0];
    size_t obase = ((size_t)(b * 512 + qt * 64 + wave * 16 + l15)) * 1024 + h * 64 + quad * 4;
    #pragma unroll
    for (int dt = 0; dt < 4; ++dt) {
        uint2 pk;
        pk.x = pk_bf16(o[dt][0] * il, o[dt][1] * il);
        pk.y = pk_bf16(o[dt][2] * il, o[dt][3] * il);
        *(uint2*)(Out + obase + dt * 16) = pk;
    }
}

// ---------------------------------------------------------------------------
extern "C" void kernel_launch(void* const* d_in, const int* in_sizes, int n_in,
                              void* d_out, int out_size, void* d_ws, size_t ws_size,
                              hipStream_t stream) {
    const float* text     = (const float*)d_in[0];
    const float* features = (const float*)d_in[1];
    const float* W_q      = (const float*)d_in[2];
    const float* b_q      = (const float*)d_in[3];
    const float* W_k      = (const float*)d_in[4];
    const float* b_k      = (const float*)d_in[5];
    const float* W_o      = (const float*)d_in[6];
    const float* b_o      = (const float*)d_in[7];
    const float* g_feat   = (const float*)d_in[8];
    const float* g_q      = (const float*)d_in[9];
    const float* g_k      = (const float*)d_in[10];

    char* ws = (char*)d_ws;
    u16* text_bf  = (u16*)(ws + 0);            //  8 MB [4096,1024]
    u16* Wq_bf    = (u16*)(ws + 8388608);      //  2 MB
    u16* Wk_bf    = (u16*)(ws + 10485760);     //  2 MB
    u16* Wo_bf    = (u16*)(ws + 12582912);     //  2 MB
    u16* feats_bf = (u16*)(ws + 14680064);     // 16 MB [8192,1024]
    u16* Vt       = (u16*)(ws + 31457280);     // 16 MB [8][1024 d][1024 n]
    u16* QKbuf    = (u16*)(ws + 48234496);     // 24 MB [12288,1024] (Q rows 0..4095, K after)
    u16* attn_bf  = (u16*)(ws + 73400320);     //  8 MB [4096,1024]

    const float QSCALE = 0.18033688011112042f; // 0.125 * log2(e)

    cast4_kernel<<<7168, 256, 0, stream>>>(text, W_q, W_k, W_o, text_bf, Wq_bf, Wk_bf, Wo_bf);

    rmsnorm_kernel<<<8192, 256, 0, stream>>>(features, g_feat, feats_bf, 1.0f);
    transpose_kernel<<<dim3(16, 16, 8), 256, 0, stream>>>(feats_bf, Vt);

    gemm_qk_kernel<<<1536, 256, 0, stream>>>(text_bf, Wq_bf, feats_bf, Wk_bf, b_q, b_k, QKbuf);
    rmsnorm_qk_kernel<<<12288, 256, 0, stream>>>(QKbuf, g_q, g_k, QSCALE);

    attn_kernel<<<dim3(128, 8), 256, 0, stream>>>(QKbuf, QKbuf + 4096 * 1024, Vt, attn_bf);

    gemm_o_kernel<<<512, 256, 0, stream>>>(attn_bf, Wo_bf, b_o, (float*)d_out);
}